// Round 11
// baseline (136.386 us; speedup 1.0000x reference)
//
#include <hip/hip_runtime.h>
#include <hip/hip_bf16.h>
#include <math.h>

// GAT, 3 layers, N=4096, H=8, O=64, F_in=256 then 512.
// Sparse softmax over ~1%-dense adj (+self loops) is EXACT vs masked dense.
//
// R2-R8: MFMA GEMMs; fused prep/sd/convA; fp16 Wh gather everywhere
//        (absmax pinned at 4.88e-4 comparison floor throughout).
// R9: gemm1 plain fp16 (Keff=256); attn gather 4 chains (32/iter).
// R10: FIX R9's prep-grid bug — convA needs 1024 blocks (4096*64 float4
//      elems / 256 thr), convW1 needs 64 blocks (16384/256). R9 gave them
//      256/32 -> 3/4 of Ac1 and 1/2 of Bc1 stayed 0xAA poison.

#define NODES 4096
#define HEADS 8
#define HID   64
#define FOUT  512   // HEADS*HID
#define MAXNBR 128

typedef _Float16 half8 __attribute__((ext_vector_type(8)));
typedef _Float16 half4 __attribute__((ext_vector_type(4)));
typedef float f32x4 __attribute__((ext_vector_type(4)));

// ---------------------------------------------------------------------------
// device helpers for the fused prep kernel
// ---------------------------------------------------------------------------
__device__ inline void conv_a_elem(const float* __restrict__ in,
                                   _Float16* __restrict__ out, int K, int id) {
  // plain fp16 A [4096][K]; id in [0, NODES*K/4)
  int perRow = K >> 2;
  int m = id / perRow, c = (id - m * perRow) * 4;
  float4 v = *(const float4*)(in + (size_t)m * K + c);
  half4 hi;
  hi[0] = (_Float16)v.x; hi[1] = (_Float16)v.y;
  hi[2] = (_Float16)v.z; hi[3] = (_Float16)v.w;
  *(half4*)(out + (size_t)m * K + c) = hi;
}

__device__ inline void conv_w_elem(const float* __restrict__ W,
                                   _Float16* __restrict__ Bc, int K, int id) {
  // plain fp16 B [512][K] (n-major); id in [0, HEADS*64*K/8)
  int n = id & 63;
  int r = id >> 6;
  int kchunks = K >> 3;
  int kc = r % kchunks, h = r / kchunks;
  int k0 = kc * 8;
  half8 hi;
#pragma unroll
  for (int i = 0; i < 8; ++i)
    hi[i] = (_Float16)W[((size_t)h * K + k0 + i) * 64 + n];
  *(half8*)(Bc + (size_t)(h * 64 + n) * K + k0) = hi;
}

// ---------------------------------------------------------------------------
// Fused prep: block-range partitioned. Element counts per range:
//   build_nbr: 4096 rows / 4 waves-per-block          -> 1024 blocks [0,1024)
//   convA:     4096*256/4 = 262144 f4-elems / 256 thr -> 1024 blocks [1024,2048)
//   convW1:    8*64*(256/8) = 16384 / 256             ->   64 blocks [2048,2112)
//   convW2:    8*64*(512/8) = 32768 / 256             ->  128 blocks [2112,2240)
//   convW3:    same                                    ->  128 blocks [2240,2368)
// ---------------------------------------------------------------------------
__global__ __launch_bounds__(256) void prep_kernel(
    const float* __restrict__ adj, int* __restrict__ nbr_cnt,
    int* __restrict__ nbr, const float* __restrict__ features,
    _Float16* __restrict__ Ac1,
    const float* __restrict__ W1, const float* __restrict__ W2,
    const float* __restrict__ W3, _Float16* __restrict__ Bc1,
    _Float16* __restrict__ Bc2, _Float16* __restrict__ Bc3) {
  const int b = blockIdx.x;
  if (b < 1024) {
    int wave = b * 4 + (threadIdx.x >> 6);
    int lane = threadIdx.x & 63;
    const float4* arow = (const float4*)(adj + (size_t)wave * NODES);
    int* lst = nbr + (size_t)wave * MAXNBR;
    int base = 0;
    float4 a0 = arow[lane];
    float4 a1 = arow[64 + lane];
#pragma unroll 4
    for (int it = 0; it < 16; ++it) {
      float4 cur = a0;
      a0 = a1;
      if (it + 2 < 16) a1 = arow[(it + 2) * 64 + lane];
      const int colbase = it * 256 + lane * 4;
#pragma unroll
      for (int c = 0; c < 4; ++c) {
        float v = (c == 0) ? cur.x : (c == 1) ? cur.y : (c == 2) ? cur.z : cur.w;
        unsigned long long mask = __ballot(v > 0.0f);
        if (v > 0.0f) {
          int pos = base + __popcll(mask & ((1ull << lane) - 1ull));
          if (pos < MAXNBR) lst[pos] = colbase + c;
        }
        base += __popcll(mask);
      }
    }
    if (lane == 0) nbr_cnt[wave] = base < MAXNBR ? base : MAXNBR;
  } else if (b < 2048) {
    conv_a_elem(features, Ac1, 256, (b - 1024) * 256 + threadIdx.x);
  } else if (b < 2112) {
    conv_w_elem(W1, Bc1, 256, (b - 2048) * 256 + threadIdx.x);
  } else if (b < 2240) {
    conv_w_elem(W2, Bc2, 512, (b - 2112) * 256 + threadIdx.x);
  } else {
    conv_w_elem(W3, Bc3, 512, (b - 2240) * 256 + threadIdx.x);
  }
}

// ---------------------------------------------------------------------------
// C16[4096,512] = A[4096,Keff] * B[512,Keff]^T (fp16 in, fp32 accum, fp16 out)
// 64x64 tile, BK=32, 4 waves, 2x2 frags of 16x16x32 MFMA.
// Fused epilogue: s[h,m], d[h,m] computed fp32-exact from accumulators.
// ---------------------------------------------------------------------------
__global__ __launch_bounds__(256) void gemm_mfma(
    const _Float16* __restrict__ A,   // [4096][Keff]
    const _Float16* __restrict__ B,   // [512][Keff]  (n-major)
    _Float16* __restrict__ C16,       // [4096][512]
    const float* __restrict__ a_src,  // [8][64]
    const float* __restrict__ a_dst,  // [8][64]
    float* __restrict__ sbuf,         // [8][4096]
    float* __restrict__ dbuf,         // [8][4096]
    int Keff) {
  __shared__ _Float16 As[64 * 40];
  __shared__ _Float16 Bs[64 * 40];
  __shared__ float sS[2][64];
  __shared__ float sD[2][64];

  const int t    = threadIdx.x;
  const int m0   = blockIdx.y * 64;
  const int n0   = blockIdx.x * 64;
  const int h    = blockIdx.x;
  const int w    = t >> 6;
  const int lane = t & 63;
  const int wr   = (w >> 1) * 32;
  const int wc   = (w & 1) * 32;
  const int lr   = lane & 15;
  const int lk   = (lane >> 4) * 8;

  const int sr = t >> 2;
  const int sc = (t & 3) * 8;
  const _Float16* gA = A + (size_t)(m0 + sr) * Keff + sc;
  const _Float16* gB = B + (size_t)(n0 + sr) * Keff + sc;

  f32x4 acc00 = {}, acc01 = {}, acc10 = {}, acc11 = {};

  half8 av = *(const half8*)(gA);
  half8 bv = *(const half8*)(gB);

  for (int k0 = 0; k0 < Keff; k0 += 32) {
    __syncthreads();
    *(half8*)(&As[sr * 40 + sc]) = av;
    *(half8*)(&Bs[sr * 40 + sc]) = bv;
    __syncthreads();
    if (k0 + 32 < Keff) {
      av = *(const half8*)(gA + k0 + 32);
      bv = *(const half8*)(gB + k0 + 32);
    }
    half8 a0 = *(const half8*)(&As[(wr + lr) * 40 + lk]);
    half8 a1 = *(const half8*)(&As[(wr + 16 + lr) * 40 + lk]);
    half8 b0 = *(const half8*)(&Bs[(wc + lr) * 40 + lk]);
    half8 b1 = *(const half8*)(&Bs[(wc + 16 + lr) * 40 + lk]);
    acc00 = __builtin_amdgcn_mfma_f32_16x16x32_f16(a0, b0, acc00, 0, 0, 0);
    acc01 = __builtin_amdgcn_mfma_f32_16x16x32_f16(a0, b1, acc01, 0, 0, 0);
    acc10 = __builtin_amdgcn_mfma_f32_16x16x32_f16(a1, b0, acc10, 0, 0, 0);
    acc11 = __builtin_amdgcn_mfma_f32_16x16x32_f16(a1, b1, acc11, 0, 0, 0);
  }

  // C/D layout: col = lane&15, row = (lane>>4)*4 + reg  [m89/m91 verified]
  const int cm = (lane >> 4) * 4;
#pragma unroll
  for (int j = 0; j < 4; ++j) {
    int m  = m0 + wr + cm + j;
    int m2 = m + 16;
    C16[(size_t)m * FOUT + n0 + wc + lr]       = (_Float16)acc00[j];
    C16[(size_t)m * FOUT + n0 + wc + 16 + lr]  = (_Float16)acc01[j];
    C16[(size_t)m2 * FOUT + n0 + wc + lr]      = (_Float16)acc10[j];
    C16[(size_t)m2 * FOUT + n0 + wc + 16 + lr] = (_Float16)acc11[j];
  }

  // fused s/d epilogue (fp32-exact from accumulators)
  const float as0 = a_src[(h << 6) + wc + lr];
  const float as1 = a_src[(h << 6) + wc + 16 + lr];
  const float ad0 = a_dst[(h << 6) + wc + lr];
  const float ad1 = a_dst[(h << 6) + wc + 16 + lr];
  float ps[8], pd[8];
#pragma unroll
  for (int j = 0; j < 4; ++j) {
    ps[j]     = acc00[j] * as0 + acc01[j] * as1;
    ps[4 + j] = acc10[j] * as0 + acc11[j] * as1;
    pd[j]     = acc00[j] * ad0 + acc01[j] * ad1;
    pd[4 + j] = acc10[j] * ad0 + acc11[j] * ad1;
  }
#pragma unroll
  for (int off = 1; off < 16; off <<= 1) {
#pragma unroll
    for (int j = 0; j < 8; ++j) {
      ps[j] += __shfl_xor(ps[j], off);
      pd[j] += __shfl_xor(pd[j], off);
    }
  }
  if (lr == 0) {
#pragma unroll
    for (int j = 0; j < 4; ++j) {
      sS[w & 1][wr + cm + j]      = ps[j];
      sS[w & 1][wr + 16 + cm + j] = ps[4 + j];
      sD[w & 1][wr + cm + j]      = pd[j];
      sD[w & 1][wr + 16 + cm + j] = pd[4 + j];
    }
  }
  __syncthreads();
  if (t < 64) {
    sbuf[(size_t)h * NODES + m0 + t] = sS[0][t] + sS[1][t];
    dbuf[(size_t)h * NODES + m0 + t] = sD[0][t] + sD[1][t];
  }
}

// ---------------------------------------------------------------------------
// Sparse masked softmax + PV + ELU. fp16 Wh16 gather, 4 chains (32 nbrs/iter).
// WRITE_AC=1: write next layer's A as fp16 [4096][512]. =0: fp32 out.
// ---------------------------------------------------------------------------
template <int WRITE_AC>
__global__ __launch_bounds__(512) void attn_kernel(
    const int* __restrict__ nbr_cnt, const int* __restrict__ nbr,
    const float* __restrict__ s, const float* __restrict__ d,
    const _Float16* __restrict__ Wh16,
    float* __restrict__ out, _Float16* __restrict__ Ac) {
  __shared__ int   lst_lds[MAXNBR];
  __shared__ float w_lds[HEADS][MAXNBR];

  const int i    = blockIdx.x;
  const int tid  = threadIdx.x;
  const int h    = tid >> 6;
  const int lane = tid & 63;
  const int cnt  = nbr_cnt[i];

  if (tid < MAXNBR)
    lst_lds[tid] = (tid < cnt) ? nbr[(size_t)i * MAXNBR + tid] : i;
  __syncthreads();

  const float s_i = s[(size_t)h * NODES + i];
  const float* dh = d + (size_t)h * NODES;
  float e0 = -1e30f, e1 = -1e30f;
  if (lane < cnt) {
    float e = s_i + dh[lst_lds[lane]];
    e0 = (e >= 0.0f) ? e : 0.2f * e;
  }
  if (lane + 64 < cnt) {
    float e = s_i + dh[lst_lds[lane + 64]];
    e1 = (e >= 0.0f) ? e : 0.2f * e;
  }
  float m = fmaxf(e0, e1);
#pragma unroll
  for (int off = 32; off; off >>= 1) m = fmaxf(m, __shfl_xor(m, off));
  float w0 = (lane < cnt) ? __expf(e0 - m) : 0.0f;
  float w1 = (lane + 64 < cnt) ? __expf(e1 - m) : 0.0f;
  w_lds[h][lane]      = w0;
  w_lds[h][lane + 64] = w1;
  float den = w0 + w1;
#pragma unroll
  for (int off = 32; off; off >>= 1) den += __shfl_xor(den, off);
  const float rden = 1.0f / den;
  __syncthreads();

  // gather: 8 subgroups of 8 lanes; lane covers 8 dims via half8; 4 chains.
  const int g  = lane >> 3;
  const int d8 = (lane & 7) * 8;
  const int cnt32 = (cnt + 31) & ~31;
  float aA[8] = {}, aB[8] = {}, aC[8] = {}, aD[8] = {};
  for (int t0 = 0; t0 < cnt32; t0 += 32) {
    const int ta = t0 + g;
    const int tb = ta + 8;
    const int tc = ta + 16;
    const int td = ta + 24;
    const int ja = lst_lds[ta], jb = lst_lds[tb];
    const int jc = lst_lds[tc], jd = lst_lds[td];
    const float wa = w_lds[h][ta], wb = w_lds[h][tb];
    const float wc = w_lds[h][tc], wd = w_lds[h][td];
    const half8 va = *(const half8*)(Wh16 + (size_t)ja * FOUT + h * HID + d8);
    const half8 vb = *(const half8*)(Wh16 + (size_t)jb * FOUT + h * HID + d8);
    const half8 vc = *(const half8*)(Wh16 + (size_t)jc * FOUT + h * HID + d8);
    const half8 vd = *(const half8*)(Wh16 + (size_t)jd * FOUT + h * HID + d8);
#pragma unroll
    for (int q = 0; q < 8; ++q) {
      aA[q] += wa * (float)va[q];
      aB[q] += wb * (float)vb[q];
      aC[q] += wc * (float)vc[q];
      aD[q] += wd * (float)vd[q];
    }
  }
  float acc[8];
#pragma unroll
  for (int q = 0; q < 8; ++q) acc[q] = (aA[q] + aB[q]) + (aC[q] + aD[q]);
#pragma unroll
  for (int off = 8; off <= 32; off <<= 1)
#pragma unroll
    for (int q = 0; q < 8; ++q) acc[q] += __shfl_xor(acc[q], off);

  if (lane < 8) {
    float o[8];
#pragma unroll
    for (int q = 0; q < 8; ++q) {
      float v = acc[q] * rden;
      o[q] = (v > 0.0f) ? v : (__expf(v) - 1.0f);
    }
    if (WRITE_AC) {
      half8 hi;
#pragma unroll
      for (int q = 0; q < 8; ++q) hi[q] = (_Float16)o[q];
      *(half8*)(Ac + (size_t)i * FOUT + h * HID + d8) = hi;
    } else {
      float* ob = out + (size_t)i * FOUT + h * HID + d8;
      *(float4*)(ob)     = make_float4(o[0], o[1], o[2], o[3]);
      *(float4*)(ob + 4) = make_float4(o[4], o[5], o[6], o[7]);
    }
  }
}

// ---------------------------------------------------------------------------
extern "C" void kernel_launch(void* const* d_in, const int* in_sizes, int n_in,
                              void* d_out, int out_size, void* d_ws,
                              size_t ws_size, hipStream_t stream) {
  const float* features = (const float*)d_in[0];
  const float* adj      = (const float*)d_in[1];
  const float* W1  = (const float*)d_in[2];
  const float* a1s = (const float*)d_in[3];
  const float* a1d = (const float*)d_in[4];
  const float* W2  = (const float*)d_in[5];
  const float* a2s = (const float*)d_in[6];
  const float* a2d = (const float*)d_in[7];
  const float* W3  = (const float*)d_in[8];
  const float* a3s = (const float*)d_in[9];
  const float* a3d = (const float*)d_in[10];
  float* out = (float*)d_out;

  char* ws = (char*)d_ws;
  size_t off = 0;
  int* nbr_cnt = (int*)(ws + off); off += (size_t)NODES * 4;
  int* nbr     = (int*)(ws + off); off += (size_t)NODES * MAXNBR * 4;
  _Float16* Wh16 = (_Float16*)(ws + off); off += (size_t)NODES * FOUT * 2;
  float* sbuf  = (float*)(ws + off); off += (size_t)HEADS * NODES * 4;
  float* dbuf  = (float*)(ws + off); off += (size_t)HEADS * NODES * 4;
  _Float16* Ac1 = (_Float16*)(ws + off); off += (size_t)NODES * 256 * 2;   // layer-1 A (fp16)
  _Float16* Ac2 = (_Float16*)(ws + off); off += (size_t)NODES * FOUT * 2;  // layers 2/3 A
  _Float16* Bc1 = (_Float16*)(ws + off); off += (size_t)FOUT * 256 * 2;
  _Float16* Bc2 = (_Float16*)(ws + off); off += (size_t)FOUT * 512 * 2;
  _Float16* Bc3 = (_Float16*)(ws + off); off += (size_t)FOUT * 512 * 2;

  prep_kernel<<<2368, 256, 0, stream>>>(adj, nbr_cnt, nbr, features, Ac1,
                                        W1, W2, W3, Bc1, Bc2, Bc3);

  dim3 gg(HEADS, NODES / 64);

  // ---- layer 1 (Keff=256, plain fp16) ----
  gemm_mfma<<<gg, 256, 0, stream>>>(Ac1, Bc1, Wh16, a1s, a1d, sbuf, dbuf, 256);
  attn_kernel<1><<<NODES, 512, 0, stream>>>(nbr_cnt, nbr, sbuf, dbuf, Wh16, out, Ac2);
  // ---- layer 2 (Keff=512, plain fp16) ----
  gemm_mfma<<<gg, 256, 0, stream>>>(Ac2, Bc2, Wh16, a2s, a2d, sbuf, dbuf, 512);
  attn_kernel<1><<<NODES, 512, 0, stream>>>(nbr_cnt, nbr, sbuf, dbuf, Wh16, out, Ac2);
  // ---- layer 3 (Keff=512, plain fp16) ----
  gemm_mfma<<<gg, 256, 0, stream>>>(Ac2, Bc3, Wh16, a3s, a3d, sbuf, dbuf, 512);
  attn_kernel<0><<<NODES, 512, 0, stream>>>(nbr_cnt, nbr, sbuf, dbuf, Wh16, out, Ac2);
}

// Round 12
// 115.900 us; speedup vs baseline: 1.1768x; 1.1768x over previous
//
#include <hip/hip_runtime.h>
#include <hip/hip_bf16.h>
#include <math.h>

// GAT, 3 layers, N=4096, H=8, O=64, F_in=256 then 512.
// Sparse softmax over ~1%-dense adj (+self loops) is EXACT vs masked dense.
//
// R2-R8: MFMA GEMMs; fused prep/sd/convA; fp16 Wh gather everywhere.
// R9/R10: gemm1 plain fp16; prep grid fixed (R10).
// R11(this): attn gather back to 16-nbr granularity (R9's 32-granularity
//     padded ~25% extra loads -> regression) with SOFTWARE PREFETCH:
//     next iteration's 2 rows load while current FMAs run (4 loads in flight).

#define NODES 4096
#define HEADS 8
#define HID   64
#define FOUT  512   // HEADS*HID
#define MAXNBR 128

typedef _Float16 half8 __attribute__((ext_vector_type(8)));
typedef _Float16 half4 __attribute__((ext_vector_type(4)));
typedef float f32x4 __attribute__((ext_vector_type(4)));

// ---------------------------------------------------------------------------
// device helpers for the fused prep kernel
// ---------------------------------------------------------------------------
__device__ inline void conv_a_elem(const float* __restrict__ in,
                                   _Float16* __restrict__ out, int K, int id) {
  // plain fp16 A [4096][K]; id in [0, NODES*K/4)
  int perRow = K >> 2;
  int m = id / perRow, c = (id - m * perRow) * 4;
  float4 v = *(const float4*)(in + (size_t)m * K + c);
  half4 hi;
  hi[0] = (_Float16)v.x; hi[1] = (_Float16)v.y;
  hi[2] = (_Float16)v.z; hi[3] = (_Float16)v.w;
  *(half4*)(out + (size_t)m * K + c) = hi;
}

__device__ inline void conv_w_elem(const float* __restrict__ W,
                                   _Float16* __restrict__ Bc, int K, int id) {
  // plain fp16 B [512][K] (n-major); id in [0, HEADS*64*K/8)
  int n = id & 63;
  int r = id >> 6;
  int kchunks = K >> 3;
  int kc = r % kchunks, h = r / kchunks;
  int k0 = kc * 8;
  half8 hi;
#pragma unroll
  for (int i = 0; i < 8; ++i)
    hi[i] = (_Float16)W[((size_t)h * K + k0 + i) * 64 + n];
  *(half8*)(Bc + (size_t)(h * 64 + n) * K + k0) = hi;
}

// ---------------------------------------------------------------------------
// Fused prep: block-range partitioned. Element counts per range:
//   build_nbr: 4096 rows / 4 waves-per-block          -> 1024 blocks [0,1024)
//   convA:     4096*256/4 = 262144 f4-elems / 256 thr -> 1024 blocks [1024,2048)
//   convW1:    8*64*(256/8) = 16384 / 256             ->   64 blocks [2048,2112)
//   convW2:    8*64*(512/8) = 32768 / 256             ->  128 blocks [2112,2240)
//   convW3:    same                                    ->  128 blocks [2240,2368)
// ---------------------------------------------------------------------------
__global__ __launch_bounds__(256) void prep_kernel(
    const float* __restrict__ adj, int* __restrict__ nbr_cnt,
    int* __restrict__ nbr, const float* __restrict__ features,
    _Float16* __restrict__ Ac1,
    const float* __restrict__ W1, const float* __restrict__ W2,
    const float* __restrict__ W3, _Float16* __restrict__ Bc1,
    _Float16* __restrict__ Bc2, _Float16* __restrict__ Bc3) {
  const int b = blockIdx.x;
  if (b < 1024) {
    int wave = b * 4 + (threadIdx.x >> 6);
    int lane = threadIdx.x & 63;
    const float4* arow = (const float4*)(adj + (size_t)wave * NODES);
    int* lst = nbr + (size_t)wave * MAXNBR;
    int base = 0;
    float4 a0 = arow[lane];
    float4 a1 = arow[64 + lane];
#pragma unroll 4
    for (int it = 0; it < 16; ++it) {
      float4 cur = a0;
      a0 = a1;
      if (it + 2 < 16) a1 = arow[(it + 2) * 64 + lane];
      const int colbase = it * 256 + lane * 4;
#pragma unroll
      for (int c = 0; c < 4; ++c) {
        float v = (c == 0) ? cur.x : (c == 1) ? cur.y : (c == 2) ? cur.z : cur.w;
        unsigned long long mask = __ballot(v > 0.0f);
        if (v > 0.0f) {
          int pos = base + __popcll(mask & ((1ull << lane) - 1ull));
          if (pos < MAXNBR) lst[pos] = colbase + c;
        }
        base += __popcll(mask);
      }
    }
    if (lane == 0) nbr_cnt[wave] = base < MAXNBR ? base : MAXNBR;
  } else if (b < 2048) {
    conv_a_elem(features, Ac1, 256, (b - 1024) * 256 + threadIdx.x);
  } else if (b < 2112) {
    conv_w_elem(W1, Bc1, 256, (b - 2048) * 256 + threadIdx.x);
  } else if (b < 2240) {
    conv_w_elem(W2, Bc2, 512, (b - 2112) * 256 + threadIdx.x);
  } else {
    conv_w_elem(W3, Bc3, 512, (b - 2240) * 256 + threadIdx.x);
  }
}

// ---------------------------------------------------------------------------
// C16[4096,512] = A[4096,Keff] * B[512,Keff]^T (fp16 in, fp32 accum, fp16 out)
// 64x64 tile, BK=32, 4 waves, 2x2 frags of 16x16x32 MFMA.
// Fused epilogue: s[h,m], d[h,m] computed fp32-exact from accumulators.
// ---------------------------------------------------------------------------
__global__ __launch_bounds__(256) void gemm_mfma(
    const _Float16* __restrict__ A,   // [4096][Keff]
    const _Float16* __restrict__ B,   // [512][Keff]  (n-major)
    _Float16* __restrict__ C16,       // [4096][512]
    const float* __restrict__ a_src,  // [8][64]
    const float* __restrict__ a_dst,  // [8][64]
    float* __restrict__ sbuf,         // [8][4096]
    float* __restrict__ dbuf,         // [8][4096]
    int Keff) {
  __shared__ _Float16 As[64 * 40];
  __shared__ _Float16 Bs[64 * 40];
  __shared__ float sS[2][64];
  __shared__ float sD[2][64];

  const int t    = threadIdx.x;
  const int m0   = blockIdx.y * 64;
  const int n0   = blockIdx.x * 64;
  const int h    = blockIdx.x;
  const int w    = t >> 6;
  const int lane = t & 63;
  const int wr   = (w >> 1) * 32;
  const int wc   = (w & 1) * 32;
  const int lr   = lane & 15;
  const int lk   = (lane >> 4) * 8;

  const int sr = t >> 2;
  const int sc = (t & 3) * 8;
  const _Float16* gA = A + (size_t)(m0 + sr) * Keff + sc;
  const _Float16* gB = B + (size_t)(n0 + sr) * Keff + sc;

  f32x4 acc00 = {}, acc01 = {}, acc10 = {}, acc11 = {};

  half8 av = *(const half8*)(gA);
  half8 bv = *(const half8*)(gB);

  for (int k0 = 0; k0 < Keff; k0 += 32) {
    __syncthreads();
    *(half8*)(&As[sr * 40 + sc]) = av;
    *(half8*)(&Bs[sr * 40 + sc]) = bv;
    __syncthreads();
    if (k0 + 32 < Keff) {
      av = *(const half8*)(gA + k0 + 32);
      bv = *(const half8*)(gB + k0 + 32);
    }
    half8 a0 = *(const half8*)(&As[(wr + lr) * 40 + lk]);
    half8 a1 = *(const half8*)(&As[(wr + 16 + lr) * 40 + lk]);
    half8 b0 = *(const half8*)(&Bs[(wc + lr) * 40 + lk]);
    half8 b1 = *(const half8*)(&Bs[(wc + 16 + lr) * 40 + lk]);
    acc00 = __builtin_amdgcn_mfma_f32_16x16x32_f16(a0, b0, acc00, 0, 0, 0);
    acc01 = __builtin_amdgcn_mfma_f32_16x16x32_f16(a0, b1, acc01, 0, 0, 0);
    acc10 = __builtin_amdgcn_mfma_f32_16x16x32_f16(a1, b0, acc10, 0, 0, 0);
    acc11 = __builtin_amdgcn_mfma_f32_16x16x32_f16(a1, b1, acc11, 0, 0, 0);
  }

  // C/D layout: col = lane&15, row = (lane>>4)*4 + reg  [m89/m91 verified]
  const int cm = (lane >> 4) * 4;
#pragma unroll
  for (int j = 0; j < 4; ++j) {
    int m  = m0 + wr + cm + j;
    int m2 = m + 16;
    C16[(size_t)m * FOUT + n0 + wc + lr]       = (_Float16)acc00[j];
    C16[(size_t)m * FOUT + n0 + wc + 16 + lr]  = (_Float16)acc01[j];
    C16[(size_t)m2 * FOUT + n0 + wc + lr]      = (_Float16)acc10[j];
    C16[(size_t)m2 * FOUT + n0 + wc + 16 + lr] = (_Float16)acc11[j];
  }

  // fused s/d epilogue (fp32-exact from accumulators)
  const float as0 = a_src[(h << 6) + wc + lr];
  const float as1 = a_src[(h << 6) + wc + 16 + lr];
  const float ad0 = a_dst[(h << 6) + wc + lr];
  const float ad1 = a_dst[(h << 6) + wc + 16 + lr];
  float ps[8], pd[8];
#pragma unroll
  for (int j = 0; j < 4; ++j) {
    ps[j]     = acc00[j] * as0 + acc01[j] * as1;
    ps[4 + j] = acc10[j] * as0 + acc11[j] * as1;
    pd[j]     = acc00[j] * ad0 + acc01[j] * ad1;
    pd[4 + j] = acc10[j] * ad0 + acc11[j] * ad1;
  }
#pragma unroll
  for (int off = 1; off < 16; off <<= 1) {
#pragma unroll
    for (int j = 0; j < 8; ++j) {
      ps[j] += __shfl_xor(ps[j], off);
      pd[j] += __shfl_xor(pd[j], off);
    }
  }
  if (lr == 0) {
#pragma unroll
    for (int j = 0; j < 4; ++j) {
      sS[w & 1][wr + cm + j]      = ps[j];
      sS[w & 1][wr + 16 + cm + j] = ps[4 + j];
      sD[w & 1][wr + cm + j]      = pd[j];
      sD[w & 1][wr + 16 + cm + j] = pd[4 + j];
    }
  }
  __syncthreads();
  if (t < 64) {
    sbuf[(size_t)h * NODES + m0 + t] = sS[0][t] + sS[1][t];
    dbuf[(size_t)h * NODES + m0 + t] = sD[0][t] + sD[1][t];
  }
}

// ---------------------------------------------------------------------------
// Sparse masked softmax + PV + ELU. fp16 Wh16 gather, 16-nbr granularity,
// 2 chains + software prefetch of the next iteration's rows.
// WRITE_AC=1: write next layer's A as fp16 [4096][512]. =0: fp32 out.
// ---------------------------------------------------------------------------
template <int WRITE_AC>
__global__ __launch_bounds__(512) void attn_kernel(
    const int* __restrict__ nbr_cnt, const int* __restrict__ nbr,
    const float* __restrict__ s, const float* __restrict__ d,
    const _Float16* __restrict__ Wh16,
    float* __restrict__ out, _Float16* __restrict__ Ac) {
  __shared__ int   lst_lds[MAXNBR];
  __shared__ float w_lds[HEADS][MAXNBR];

  const int i    = blockIdx.x;
  const int tid  = threadIdx.x;
  const int h    = tid >> 6;
  const int lane = tid & 63;
  const int cnt  = nbr_cnt[i];

  if (tid < MAXNBR)
    lst_lds[tid] = (tid < cnt) ? nbr[(size_t)i * MAXNBR + tid] : i;
  __syncthreads();

  const float s_i = s[(size_t)h * NODES + i];
  const float* dh = d + (size_t)h * NODES;
  float e0 = -1e30f, e1 = -1e30f;
  if (lane < cnt) {
    float e = s_i + dh[lst_lds[lane]];
    e0 = (e >= 0.0f) ? e : 0.2f * e;
  }
  if (lane + 64 < cnt) {
    float e = s_i + dh[lst_lds[lane + 64]];
    e1 = (e >= 0.0f) ? e : 0.2f * e;
  }
  float m = fmaxf(e0, e1);
#pragma unroll
  for (int off = 32; off; off >>= 1) m = fmaxf(m, __shfl_xor(m, off));
  float w0 = (lane < cnt) ? __expf(e0 - m) : 0.0f;
  float w1 = (lane + 64 < cnt) ? __expf(e1 - m) : 0.0f;
  w_lds[h][lane]      = w0;
  w_lds[h][lane + 64] = w1;
  float den = w0 + w1;
#pragma unroll
  for (int off = 32; off; off >>= 1) den += __shfl_xor(den, off);
  const float rden = 1.0f / den;
  __syncthreads();

  // gather: 8 subgroups of 8 lanes; lane covers 8 dims via half8; 2 chains,
  // 16 nbrs/iter, next-iter rows prefetched during current FMAs.
  const int g  = lane >> 3;
  const int d8 = (lane & 7) * 8;
  const int cnt16 = (cnt + 15) & ~15;
  const _Float16* base = Wh16 + h * HID + d8;
  float aA[8] = {}, aB[8] = {};

  int ja = lst_lds[g], jb = lst_lds[g + 8];
  float wa = w_lds[h][g], wb = w_lds[h][g + 8];
  half8 va = *(const half8*)(base + (size_t)ja * FOUT);
  half8 vb = *(const half8*)(base + (size_t)jb * FOUT);

  for (int t0 = 16; t0 < cnt16; t0 += 16) {
    const int ta2 = t0 + g, tb2 = ta2 + 8;
    const int ja2 = lst_lds[ta2], jb2 = lst_lds[tb2];
    const float wa2 = w_lds[h][ta2], wb2 = w_lds[h][tb2];
    const half8 va2 = *(const half8*)(base + (size_t)ja2 * FOUT);
    const half8 vb2 = *(const half8*)(base + (size_t)jb2 * FOUT);
#pragma unroll
    for (int q = 0; q < 8; ++q) {
      aA[q] += wa * (float)va[q];
      aB[q] += wb * (float)vb[q];
    }
    wa = wa2; wb = wb2; va = va2; vb = vb2;
  }
#pragma unroll
  for (int q = 0; q < 8; ++q) {
    aA[q] += wa * (float)va[q];
    aB[q] += wb * (float)vb[q];
  }

  float acc[8];
#pragma unroll
  for (int q = 0; q < 8; ++q) acc[q] = aA[q] + aB[q];
#pragma unroll
  for (int off = 8; off <= 32; off <<= 1)
#pragma unroll
    for (int q = 0; q < 8; ++q) acc[q] += __shfl_xor(acc[q], off);

  if (lane < 8) {
    float o[8];
#pragma unroll
    for (int q = 0; q < 8; ++q) {
      float v = acc[q] * rden;
      o[q] = (v > 0.0f) ? v : (__expf(v) - 1.0f);
    }
    if (WRITE_AC) {
      half8 hi;
#pragma unroll
      for (int q = 0; q < 8; ++q) hi[q] = (_Float16)o[q];
      *(half8*)(Ac + (size_t)i * FOUT + h * HID + d8) = hi;
    } else {
      float* ob = out + (size_t)i * FOUT + h * HID + d8;
      *(float4*)(ob)     = make_float4(o[0], o[1], o[2], o[3]);
      *(float4*)(ob + 4) = make_float4(o[4], o[5], o[6], o[7]);
    }
  }
}

// ---------------------------------------------------------------------------
extern "C" void kernel_launch(void* const* d_in, const int* in_sizes, int n_in,
                              void* d_out, int out_size, void* d_ws,
                              size_t ws_size, hipStream_t stream) {
  const float* features = (const float*)d_in[0];
  const float* adj      = (const float*)d_in[1];
  const float* W1  = (const float*)d_in[2];
  const float* a1s = (const float*)d_in[3];
  const float* a1d = (const float*)d_in[4];
  const float* W2  = (const float*)d_in[5];
  const float* a2s = (const float*)d_in[6];
  const float* a2d = (const float*)d_in[7];
  const float* W3  = (const float*)d_in[8];
  const float* a3s = (const float*)d_in[9];
  const float* a3d = (const float*)d_in[10];
  float* out = (float*)d_out;

  char* ws = (char*)d_ws;
  size_t off = 0;
  int* nbr_cnt = (int*)(ws + off); off += (size_t)NODES * 4;
  int* nbr     = (int*)(ws + off); off += (size_t)NODES * MAXNBR * 4;
  _Float16* Wh16 = (_Float16*)(ws + off); off += (size_t)NODES * FOUT * 2;
  float* sbuf  = (float*)(ws + off); off += (size_t)HEADS * NODES * 4;
  float* dbuf  = (float*)(ws + off); off += (size_t)HEADS * NODES * 4;
  _Float16* Ac1 = (_Float16*)(ws + off); off += (size_t)NODES * 256 * 2;   // layer-1 A (fp16)
  _Float16* Ac2 = (_Float16*)(ws + off); off += (size_t)NODES * FOUT * 2;  // layers 2/3 A
  _Float16* Bc1 = (_Float16*)(ws + off); off += (size_t)FOUT * 256 * 2;
  _Float16* Bc2 = (_Float16*)(ws + off); off += (size_t)FOUT * 512 * 2;
  _Float16* Bc3 = (_Float16*)(ws + off); off += (size_t)FOUT * 512 * 2;

  prep_kernel<<<2368, 256, 0, stream>>>(adj, nbr_cnt, nbr, features, Ac1,
                                        W1, W2, W3, Bc1, Bc2, Bc3);

  dim3 gg(HEADS, NODES / 64);

  // ---- layer 1 (Keff=256, plain fp16) ----
  gemm_mfma<<<gg, 256, 0, stream>>>(Ac1, Bc1, Wh16, a1s, a1d, sbuf, dbuf, 256);
  attn_kernel<1><<<NODES, 512, 0, stream>>>(nbr_cnt, nbr, sbuf, dbuf, Wh16, out, Ac2);
  // ---- layer 2 (Keff=512, plain fp16) ----
  gemm_mfma<<<gg, 256, 0, stream>>>(Ac2, Bc2, Wh16, a2s, a2d, sbuf, dbuf, 512);
  attn_kernel<1><<<NODES, 512, 0, stream>>>(nbr_cnt, nbr, sbuf, dbuf, Wh16, out, Ac2);
  // ---- layer 3 (Keff=512, plain fp16) ----
  gemm_mfma<<<gg, 256, 0, stream>>>(Ac2, Bc3, Wh16, a3s, a3d, sbuf, dbuf, 512);
  attn_kernel<0><<<NODES, 512, 0, stream>>>(nbr_cnt, nbr, sbuf, dbuf, Wh16, out, Ac2);
}